// Round 1
// baseline (275.080 us; speedup 1.0000x reference)
//
#include <hip/hip_runtime.h>
#include <math.h>

#define NROWS 4096
#define DIM   512
#define BM    128
#define BK    16

// ws layout (bytes):
// [0,      16384)  float mag[4096]
// [16384,  32768)  float row_neg[4096]
// [32768,  32776)  double loss
// [32776,  32780)  unsigned int pair_cnt (triu positive pairs)
// [32784,  ...  )  pairs: 3 ints each {i, j, float_bits(dist)}

__global__ void mag_kernel(const float* __restrict__ X, float* __restrict__ mag) {
    int row  = blockIdx.x * 4 + (threadIdx.x >> 6);
    int lane = threadIdx.x & 63;
    const float4* p = reinterpret_cast<const float4*>(X + (size_t)row * DIM);
    float s = 0.f;
#pragma unroll
    for (int q = lane; q < DIM / 4; q += 64) {
        float4 v = p[q];
        s += v.x * v.x + v.y * v.y + v.z * v.z + v.w * v.w;
    }
#pragma unroll
    for (int o = 32; o; o >>= 1) s += __shfl_down(s, o);
    if (lane == 0) mag[row] = s;
}

__global__ __launch_bounds__(256) void sim_kernel(
        const float* __restrict__ X, const int* __restrict__ tgt,
        const float* __restrict__ mag, float* __restrict__ row_neg,
        unsigned int* __restrict__ pair_cnt, int* __restrict__ pairs,
        unsigned int cap) {
    __shared__ float As[BK][BM + 4];
    __shared__ float Bs[BK][BM + 4];

    const int tid = threadIdx.x;
    const int tx = tid & 15, ty = tid >> 4;
    const int rowBase = blockIdx.y * BM;
    const int colBase = blockIdx.x * BM;

    float acc[8][8] = {};

    for (int k0 = 0; k0 < DIM; k0 += BK) {
#pragma unroll
        for (int q = tid; q < 512; q += 256) {
            int r = q >> 2, c = q & 3;
            float4 v = *reinterpret_cast<const float4*>(&X[(size_t)(rowBase + r) * DIM + k0 + c * 4]);
            As[c * 4 + 0][r] = v.x; As[c * 4 + 1][r] = v.y;
            As[c * 4 + 2][r] = v.z; As[c * 4 + 3][r] = v.w;
            float4 w = *reinterpret_cast<const float4*>(&X[(size_t)(colBase + r) * DIM + k0 + c * 4]);
            Bs[c * 4 + 0][r] = w.x; Bs[c * 4 + 1][r] = w.y;
            Bs[c * 4 + 2][r] = w.z; Bs[c * 4 + 3][r] = w.w;
        }
        __syncthreads();
#pragma unroll
        for (int k = 0; k < BK; k++) {
            float a[8], b[8];
            *reinterpret_cast<float4*>(&a[0]) = *reinterpret_cast<const float4*>(&As[k][ty * 8]);
            *reinterpret_cast<float4*>(&a[4]) = *reinterpret_cast<const float4*>(&As[k][ty * 8 + 4]);
            *reinterpret_cast<float4*>(&b[0]) = *reinterpret_cast<const float4*>(&Bs[k][tx * 8]);
            *reinterpret_cast<float4*>(&b[4]) = *reinterpret_cast<const float4*>(&Bs[k][tx * 8 + 4]);
#pragma unroll
            for (int a8 = 0; a8 < 8; a8++)
#pragma unroll
                for (int b8 = 0; b8 < 8; b8++) acc[a8][b8] = fmaf(a[a8], b[b8], acc[a8][b8]);
        }
        __syncthreads();
    }

    // ---- epilogue ----
    const int ib = rowBase + ty * 8;
    const int jb = colBase + tx * 8;
    int tgi[8], tgj[8];
    float mi[8], mj[8];
#pragma unroll
    for (int a = 0; a < 8; a++) {
        tgi[a] = tgt[ib + a]; mi[a] = mag[ib + a];
        tgj[a] = tgt[jb + a]; mj[a] = mag[jb + a];
    }

    float negsum[8] = {};
    int mycnt = 0;
#pragma unroll
    for (int a = 0; a < 8; a++) {
#pragma unroll
        for (int b = 0; b < 8; b++) {
            float d2 = mi[a] + mj[b] - 2.f * acc[a][b];
            float dist = d2 > 0.f ? sqrtf(d2) : 0.f;
            if (tgi[a] != tgj[b]) {
                if (dist != 0.f) negsum[a] += expf(1.0f - dist);
            } else if (ib + a < jb + b) {
                mycnt++;
            }
        }
    }

    if (mycnt) {
        unsigned int base = atomicAdd(pair_cnt, (unsigned int)mycnt);
        unsigned int off = 0;
#pragma unroll
        for (int a = 0; a < 8; a++) {
#pragma unroll
            for (int b = 0; b < 8; b++) {
                if (tgi[a] == tgj[b] && (ib + a) < (jb + b)) {
                    unsigned int idx = base + off;
                    if (idx < cap) {
                        float d2 = mi[a] + mj[b] - 2.f * acc[a][b];
                        float dist = d2 > 0.f ? sqrtf(d2) : 0.f;
                        pairs[idx * 3 + 0] = ib + a;
                        pairs[idx * 3 + 1] = jb + b;
                        pairs[idx * 3 + 2] = __float_as_int(dist);
                    }
                    off++;
                }
            }
        }
    }

    // block-reduce negsum per row, one atomic per row
    __syncthreads();
    float* red = &As[0][0];  // 128*16 floats = 8192 B fits in As (8448 B)
#pragma unroll
    for (int a = 0; a < 8; a++) red[(ty * 8 + a) * 16 + tx] = negsum[a];
    __syncthreads();
    if (tid < 128) {
        float s = 0.f;
#pragma unroll
        for (int t = 0; t < 16; t++) s += red[tid * 16 + t];
        atomicAdd(&row_neg[rowBase + tid], s);
    }
}

__global__ void pair_kernel(const int* __restrict__ pairs,
                            const unsigned int* __restrict__ pair_cnt,
                            const float* __restrict__ row_neg,
                            unsigned int cap, double* __restrict__ loss) {
    __shared__ double red[256];
    unsigned int n = *pair_cnt;
    if (n > cap) n = cap;
    double local = 0.0;
    for (unsigned int p = blockIdx.x * blockDim.x + threadIdx.x; p < n;
         p += gridDim.x * blockDim.x) {
        int i = pairs[3 * p], j = pairs[3 * p + 1];
        float d = __int_as_float(pairs[3 * p + 2]);
        float J = logf(row_neg[i] + row_neg[j]) + d;
        if (J > 0.f) local += (double)J * (double)J;
    }
    red[threadIdx.x] = local;
    __syncthreads();
    for (int s = 128; s; s >>= 1) {
        if (threadIdx.x < (unsigned)s) red[threadIdx.x] += red[threadIdx.x + s];
        __syncthreads();
    }
    if (threadIdx.x == 0) atomicAdd(loss, red[0]);
}

__global__ void fin_kernel(const double* __restrict__ loss,
                           const unsigned int* __restrict__ pair_cnt,
                           float* __restrict__ out) {
    // len_p is the full symmetric positive count = 2 * triu count
    out[0] = (float)(*loss / (2.0 * (double)(*pair_cnt)));
}

extern "C" void kernel_launch(void* const* d_in, const int* in_sizes, int n_in,
                              void* d_out, int out_size, void* d_ws, size_t ws_size,
                              hipStream_t stream) {
    const float* X = (const float*)d_in[0];
    const int* tgt = (const int*)d_in[1];
    float* out = (float*)d_out;

    char* ws = (char*)d_ws;
    float* mag = (float*)(ws + 0);
    float* row_neg = (float*)(ws + 16384);
    double* loss = (double*)(ws + 32768);
    unsigned int* pair_cnt = (unsigned int*)(ws + 32776);
    int* pairs = (int*)(ws + 32784);
    unsigned int cap = 0;
    if (ws_size > 32784 + 12) cap = (unsigned int)((ws_size - 32784) / 12);

    // zero row_neg, loss, pair_cnt
    hipMemsetAsync(ws + 16384, 0, 16400, stream);

    mag_kernel<<<NROWS / 4, 256, 0, stream>>>(X, mag);

    dim3 grid(NROWS / BM, NROWS / BM);
    sim_kernel<<<grid, 256, 0, stream>>>(X, tgt, mag, row_neg, pair_cnt, pairs, cap);

    pair_kernel<<<256, 256, 0, stream>>>(pairs, pair_cnt, row_neg, cap, loss);

    fin_kernel<<<1, 1, 0, stream>>>(loss, pair_cnt, out);
}

// Round 2
// 104.318 us; speedup vs baseline: 2.6369x; 2.6369x over previous
//
#include <hip/hip_runtime.h>
#include <math.h>

#define NROWS 4096
#define DIM   512
#define BM    128
#define BN    128
#define BK    64

typedef __attribute__((ext_vector_type(4))) float f32x4;
typedef __attribute__((ext_vector_type(8))) short bf16x8;

// ws layout (bytes):
// [0,       16384)   float mag[4096]
// [16384,   32768)   float row_neg[4096]
// [32768,   32776)   double loss
// [32776,   32780)   unsigned int pair_cnt
// [32800,   4227104) unsigned short Xb[4096*512]  (bf16 copy of X)
// [4227104, ...)     pairs: 3 ints each {i, j, float_bits(dist)}
#define XB_OFF   32800
#define PAIR_OFF 4227104

__device__ inline unsigned short f2bf(float f) {
    unsigned int u = __float_as_uint(f);
    unsigned int r = (u + 0x7fffu + ((u >> 16) & 1u)) >> 16;   // RTNE
    return (unsigned short)r;
}

__global__ void convert_kernel(const float* __restrict__ X,
                               unsigned short* __restrict__ Xb) {
    int idx = blockIdx.x * blockDim.x + threadIdx.x;  // one per 4 elements
    float4 v = reinterpret_cast<const float4*>(X)[idx];
    short4 o;
    o.x = (short)f2bf(v.x); o.y = (short)f2bf(v.y);
    o.z = (short)f2bf(v.z); o.w = (short)f2bf(v.w);
    reinterpret_cast<short4*>(Xb)[idx] = o;
}

__global__ void mag_kernel(const float* __restrict__ X, float* __restrict__ mag) {
    int row  = blockIdx.x * 4 + (threadIdx.x >> 6);
    int lane = threadIdx.x & 63;
    const float4* p = reinterpret_cast<const float4*>(X + (size_t)row * DIM);
    float s = 0.f;
#pragma unroll
    for (int q = lane; q < DIM / 4; q += 64) {
        float4 v = p[q];
        s += v.x * v.x + v.y * v.y + v.z * v.z + v.w * v.w;
    }
#pragma unroll
    for (int o = 32; o; o >>= 1) s += __shfl_down(s, o);
    if (lane == 0) mag[row] = s;
}

__global__ __launch_bounds__(256) void sim_mfma(
        const unsigned short* __restrict__ Xb, const int* __restrict__ tgt,
        const float* __restrict__ mag, float* __restrict__ row_neg,
        unsigned int* __restrict__ pair_cnt, int* __restrict__ pairs,
        unsigned int cap) {
    __shared__ unsigned short As[BM * BK];   // 16 KB
    __shared__ unsigned short Bs[BM * BK];   // 16 KB

    const int tid  = threadIdx.x;
    const int lane = tid & 63;
    const int wid  = tid >> 6;        // 4 waves: 2x2 of 64x64
    const int wr   = wid >> 1, wc = wid & 1;
    const int rowBase = blockIdx.y * BM;
    const int colBase = blockIdx.x * BN;
    const int l15 = lane & 15;
    const int lg  = lane >> 4;        // 0..3

    f32x4 acc[4][4];
#pragma unroll
    for (int m = 0; m < 4; m++)
#pragma unroll
        for (int n = 0; n < 4; n++) acc[m][n] = (f32x4){0.f, 0.f, 0.f, 0.f};

    for (int k0 = 0; k0 < DIM; k0 += BK) {
        __syncthreads();   // previous iteration's reads done before overwrite
        // stage A,B tiles: 1024 16B-chunks each; 4 gload_lds calls/wave/operand.
        // LDS slot (row r, chunk s) holds global chunk s^(r&7)  (read-side XOR).
#pragma unroll
        for (int c = 0; c < 4; c++) {
            int chunkBase = (c * 4 + wid) * 64;      // wave-uniform
            int idx = chunkBase + lane;              // 0..1023
            int r   = idx >> 3;
            int ch  = idx & 7;
            int gch = ch ^ (r & 7);
            const unsigned short* ga = Xb + (size_t)(rowBase + r) * DIM + k0 + gch * 8;
            __builtin_amdgcn_global_load_lds(
                (const __attribute__((address_space(1))) void*)ga,
                (__attribute__((address_space(3))) void*)(As + chunkBase * 8),
                16, 0, 0);
            const unsigned short* gb = Xb + (size_t)(colBase + r) * DIM + k0 + gch * 8;
            __builtin_amdgcn_global_load_lds(
                (const __attribute__((address_space(1))) void*)gb,
                (__attribute__((address_space(3))) void*)(Bs + chunkBase * 8),
                16, 0, 0);
        }
        __syncthreads();   // compiler drains vmcnt before barrier

#pragma unroll
        for (int ksub = 0; ksub < 2; ksub++) {
            bf16x8 af[4], bf[4];
#pragma unroll
            for (int m = 0; m < 4; m++) {
                int ra = wr * 64 + m * 16 + l15;
                int ch = (ksub * 4 + lg) ^ (ra & 7);
                af[m] = *reinterpret_cast<const bf16x8*>(&As[ra * BK + ch * 8]);
            }
#pragma unroll
            for (int n = 0; n < 4; n++) {
                int rb = wc * 64 + n * 16 + l15;
                int ch = (ksub * 4 + lg) ^ (rb & 7);
                bf[n] = *reinterpret_cast<const bf16x8*>(&Bs[rb * BK + ch * 8]);
            }
#pragma unroll
            for (int m = 0; m < 4; m++)
#pragma unroll
                for (int n = 0; n < 4; n++)
                    acc[m][n] = __builtin_amdgcn_mfma_f32_16x16x32_bf16(
                        af[m], bf[n], acc[m][n], 0, 0, 0);
        }
    }

    // ---- fused epilogue ----
    // C/D layout: col = lane&15, row = (lane>>4)*4 + reg
    int   gcol[4], tgj[4];
    float mj[4];
#pragma unroll
    for (int n = 0; n < 4; n++) {
        gcol[n] = colBase + wc * 64 + n * 16 + l15;
        tgj[n]  = tgt[gcol[n]];
        mj[n]   = mag[gcol[n]];
    }
    int   grow[4][4], tgi[4][4];
    float mi[4][4];
#pragma unroll
    for (int m = 0; m < 4; m++)
#pragma unroll
        for (int q = 0; q < 4; q++) {
            grow[m][q] = rowBase + wr * 64 + m * 16 + lg * 4 + q;
            tgi[m][q]  = tgt[grow[m][q]];
            mi[m][q]   = mag[grow[m][q]];
        }

    float negsum[4][4];
#pragma unroll
    for (int m = 0; m < 4; m++)
#pragma unroll
        for (int q = 0; q < 4; q++) negsum[m][q] = 0.f;

    int mycnt = 0;
#pragma unroll
    for (int m = 0; m < 4; m++)
#pragma unroll
        for (int n = 0; n < 4; n++)
#pragma unroll
            for (int q = 0; q < 4; q++) {
                float sim  = acc[m][n][q];
                float d2   = mi[m][q] + mj[n] - 2.f * sim;
                float dist = d2 > 0.f ? sqrtf(d2) : 0.f;
                if (tgi[m][q] != tgj[n]) {
                    if (dist != 0.f) negsum[m][q] += __expf(1.0f - dist);
                } else if (grow[m][q] < gcol[n]) {
                    mycnt++;
                }
            }

    // per-row reduce across the 16 lanes of each lane-group, 1 atomic/row
#pragma unroll
    for (int m = 0; m < 4; m++)
#pragma unroll
        for (int q = 0; q < 4; q++) {
            float v = negsum[m][q];
            v += __shfl_xor(v, 1); v += __shfl_xor(v, 2);
            v += __shfl_xor(v, 4); v += __shfl_xor(v, 8);
            if (l15 == 0) atomicAdd(&row_neg[grow[m][q]], v);
        }

    // compact positive (i<j) pairs
    if (mycnt) {
        unsigned int base = atomicAdd(pair_cnt, (unsigned int)mycnt);
        unsigned int off = 0;
#pragma unroll
        for (int m = 0; m < 4; m++)
#pragma unroll
            for (int n = 0; n < 4; n++)
#pragma unroll
                for (int q = 0; q < 4; q++) {
                    if (tgi[m][q] == tgj[n] && grow[m][q] < gcol[n]) {
                        unsigned int idx = base + off;
                        if (idx < cap) {
                            float sim  = acc[m][n][q];
                            float d2   = mi[m][q] + mj[n] - 2.f * sim;
                            float dist = d2 > 0.f ? sqrtf(d2) : 0.f;
                            pairs[idx * 3 + 0] = grow[m][q];
                            pairs[idx * 3 + 1] = gcol[n];
                            pairs[idx * 3 + 2] = __float_as_int(dist);
                        }
                        off++;
                    }
                }
    }
}

__global__ void pair_kernel(const int* __restrict__ pairs,
                            const unsigned int* __restrict__ pair_cnt,
                            const float* __restrict__ row_neg,
                            unsigned int cap, double* __restrict__ loss) {
    __shared__ double red[256];
    unsigned int n = *pair_cnt;
    if (n > cap) n = cap;
    double local = 0.0;
    for (unsigned int p = blockIdx.x * blockDim.x + threadIdx.x; p < n;
         p += gridDim.x * blockDim.x) {
        int i = pairs[3 * p], j = pairs[3 * p + 1];
        float d = __int_as_float(pairs[3 * p + 2]);
        float J = logf(row_neg[i] + row_neg[j]) + d;
        if (J > 0.f) local += (double)J * (double)J;
    }
    red[threadIdx.x] = local;
    __syncthreads();
    for (int s = 128; s; s >>= 1) {
        if (threadIdx.x < (unsigned)s) red[threadIdx.x] += red[threadIdx.x + s];
        __syncthreads();
    }
    if (threadIdx.x == 0) atomicAdd(loss, red[0]);
}

__global__ void fin_kernel(const double* __restrict__ loss,
                           const unsigned int* __restrict__ pair_cnt,
                           float* __restrict__ out) {
    out[0] = (float)(*loss / (2.0 * (double)(*pair_cnt)));
}

extern "C" void kernel_launch(void* const* d_in, const int* in_sizes, int n_in,
                              void* d_out, int out_size, void* d_ws, size_t ws_size,
                              hipStream_t stream) {
    const float* X = (const float*)d_in[0];
    const int* tgt = (const int*)d_in[1];
    float* out = (float*)d_out;

    char* ws = (char*)d_ws;
    float* mag            = (float*)(ws + 0);
    float* row_neg        = (float*)(ws + 16384);
    double* loss          = (double*)(ws + 32768);
    unsigned int* pair_cnt = (unsigned int*)(ws + 32776);
    unsigned short* Xb    = (unsigned short*)(ws + XB_OFF);
    int* pairs            = (int*)(ws + PAIR_OFF);
    unsigned int cap = 0;
    if (ws_size > PAIR_OFF + 12) cap = (unsigned int)((ws_size - PAIR_OFF) / 12);

    hipMemsetAsync(ws + 16384, 0, 16400, stream);  // row_neg, loss, pair_cnt

    convert_kernel<<<(NROWS * DIM / 4) / 256, 256, 0, stream>>>(X, Xb);
    mag_kernel<<<NROWS / 4, 256, 0, stream>>>(X, mag);

    dim3 grid(NROWS / BN, NROWS / BM);
    sim_mfma<<<grid, 256, 0, stream>>>(Xb, tgt, mag, row_neg, pair_cnt, pairs, cap);

    pair_kernel<<<256, 256, 0, stream>>>(pairs, pair_cnt, row_neg, cap, loss);

    fin_kernel<<<1, 1, 0, stream>>>(loss, pair_cnt, out);
}

// Round 3
// 95.234 us; speedup vs baseline: 2.8885x; 1.0954x over previous
//
#include <hip/hip_runtime.h>
#include <math.h>

#define NROWS 4096
#define DIM   512
#define BM    128
#define BN    128
#define BK    64
#define NKT   (DIM / BK)        // 8 K-steps
#define NTILE (NROWS / BM)      // 32
#define NBLK  (NTILE * (NTILE + 1) / 2)  // 528 triangular blocks

typedef __attribute__((ext_vector_type(4))) float f32x4;
typedef __attribute__((ext_vector_type(8))) short bf16x8;

// ws layout (bytes):
// [0,       16384)   float mag[4096]
// [16384,   32768)   float row_neg[4096]
// [32768,   32776)   double loss
// [32776,   32780)   unsigned int pair_cnt
// [32800,   4227104) unsigned short Xb[4096*512]  (bf16 copy of X)
// [4227104, ...)     pairs: 3 ints each {i, j, float_bits(dist)}
#define XB_OFF   32800
#define PAIR_OFF 4227104

__device__ inline unsigned short f2bf(float f) {
    unsigned int u = __float_as_uint(f);
    unsigned int r = (u + 0x7fffu + ((u >> 16) & 1u)) >> 16;   // RTNE
    return (unsigned short)r;
}

// fused: bf16 convert + row sq-norms (reads X once)
__global__ void prep_kernel(const float* __restrict__ X,
                            unsigned short* __restrict__ Xb,
                            float* __restrict__ mag) {
    int row  = blockIdx.x * 4 + (threadIdx.x >> 6);
    int lane = threadIdx.x & 63;
    const float4* p = reinterpret_cast<const float4*>(X + (size_t)row * DIM);
    short4* o = reinterpret_cast<short4*>(Xb + (size_t)row * DIM);
    float s = 0.f;
#pragma unroll
    for (int q = lane; q < DIM / 4; q += 64) {
        float4 v = p[q];
        s += v.x * v.x + v.y * v.y + v.z * v.z + v.w * v.w;
        short4 b;
        b.x = (short)f2bf(v.x); b.y = (short)f2bf(v.y);
        b.z = (short)f2bf(v.z); b.w = (short)f2bf(v.w);
        o[q] = b;
    }
#pragma unroll
    for (int off = 32; off; off >>= 1) s += __shfl_down(s, off);
    if (lane == 0) mag[row] = s;
}

__global__ __launch_bounds__(256) void sim_mfma(
        const unsigned short* __restrict__ Xb, const int* __restrict__ tgt,
        const float* __restrict__ mag, float* __restrict__ row_neg,
        unsigned int* __restrict__ pair_cnt, int* __restrict__ pairs,
        unsigned int cap) {
    __shared__ unsigned short As[2][BM * BK];   // 2 x 16 KB
    __shared__ unsigned short Bs[2][BM * BK];   // 2 x 16 KB

    const int tid  = threadIdx.x;
    const int lane = tid & 63;
    const int wid  = tid >> 6;        // 4 waves: 2x2 of 64x64
    const int wr   = wid >> 1, wc = wid & 1;
    const int l15  = lane & 15;
    const int lg   = lane >> 4;       // 0..3

    // triangular block mapping: t -> (bi, bj), bi <= bj
    {
    }
    int t = blockIdx.x;
    int bi = (int)((65.0f - sqrtf(4225.0f - 8.0f * (float)t)) * 0.5f);
    while ((65 * (bi + 1) - (bi + 1) * (bi + 1)) / 2 <= t) bi++;
    while ((65 * bi - bi * bi) / 2 > t) bi--;
    int bj = bi + (t - (65 * bi - bi * bi) / 2);
    const int rowBase = bi * BM;
    const int colBase = bj * BM;
    const bool offd = (bi != bj);

    f32x4 acc[4][4];
#pragma unroll
    for (int m = 0; m < 4; m++)
#pragma unroll
        for (int n = 0; n < 4; n++) acc[m][n] = (f32x4){0.f, 0.f, 0.f, 0.f};

    // stage one K-tile into buffer `buf`; LDS slot (row r, chunk s) holds
    // global chunk s^(r&7) (read-side XOR, linear LDS dest - rule #21)
    auto STAGE = [&](int buf, int kt) {
        const int k0 = kt * BK;
#pragma unroll
        for (int c = 0; c < 4; c++) {
            int chunkBase = (c * 4 + wid) * 64;      // wave-uniform
            int idx = chunkBase + lane;              // 0..1023
            int r   = idx >> 3;
            int ch  = idx & 7;
            int gch = ch ^ (r & 7);
            const unsigned short* ga = Xb + (size_t)(rowBase + r) * DIM + k0 + gch * 8;
            __builtin_amdgcn_global_load_lds(
                (const __attribute__((address_space(1))) void*)ga,
                (__attribute__((address_space(3))) void*)(&As[buf][chunkBase * 8]),
                16, 0, 0);
            const unsigned short* gb = Xb + (size_t)(colBase + r) * DIM + k0 + gch * 8;
            __builtin_amdgcn_global_load_lds(
                (const __attribute__((address_space(1))) void*)gb,
                (__attribute__((address_space(3))) void*)(&Bs[buf][chunkBase * 8]),
                16, 0, 0);
        }
    };

    STAGE(0, 0);
    __syncthreads();   // drains vmcnt(0)

    for (int kt = 0; kt < NKT; kt++) {
        const int cur = kt & 1;
        if (kt + 1 < NKT) STAGE(cur ^ 1, kt + 1);   // prefetch next tile
#pragma unroll
        for (int ksub = 0; ksub < 2; ksub++) {
            bf16x8 af[4], bf[4];
#pragma unroll
            for (int m = 0; m < 4; m++) {
                int ra = wr * 64 + m * 16 + l15;
                int ch = (ksub * 4 + lg) ^ (ra & 7);
                af[m] = *reinterpret_cast<const bf16x8*>(&As[cur][ra * BK + ch * 8]);
            }
#pragma unroll
            for (int n = 0; n < 4; n++) {
                int rb = wc * 64 + n * 16 + l15;
                int ch = (ksub * 4 + lg) ^ (rb & 7);
                bf[n] = *reinterpret_cast<const bf16x8*>(&Bs[cur][rb * BK + ch * 8]);
            }
#pragma unroll
            for (int m = 0; m < 4; m++)
#pragma unroll
                for (int n = 0; n < 4; n++)
                    acc[m][n] = __builtin_amdgcn_mfma_f32_16x16x32_bf16(
                        af[m], bf[n], acc[m][n], 0, 0, 0);
        }
        __syncthreads();   // compiler drains vmcnt(0) lgkmcnt(0) here
    }

    // ---- fused epilogue ----
    // C/D layout: col = lane&15, row = (lane>>4)*4 + reg
    int   gcol[4], tgj[4];
    float mj[4];
#pragma unroll
    for (int n = 0; n < 4; n++) {
        gcol[n] = colBase + wc * 64 + n * 16 + l15;
        tgj[n]  = tgt[gcol[n]];
        mj[n]   = mag[gcol[n]];
    }
    int   grow[4][4], tgi[4][4];
    float mi[4][4];
#pragma unroll
    for (int m = 0; m < 4; m++)
#pragma unroll
        for (int q = 0; q < 4; q++) {
            grow[m][q] = rowBase + wr * 64 + m * 16 + lg * 4 + q;
            tgi[m][q]  = tgt[grow[m][q]];
            mi[m][q]   = mag[grow[m][q]];
        }

    float negrow[4][4];
    float negcol[4] = {0.f, 0.f, 0.f, 0.f};
#pragma unroll
    for (int m = 0; m < 4; m++)
#pragma unroll
        for (int q = 0; q < 4; q++) negrow[m][q] = 0.f;

    int mycnt = 0;
#pragma unroll
    for (int m = 0; m < 4; m++)
#pragma unroll
        for (int n = 0; n < 4; n++)
#pragma unroll
            for (int q = 0; q < 4; q++) {
                float sim  = acc[m][n][q];
                float d2   = mi[m][q] + mj[n] - 2.f * sim;
                float dist = d2 > 0.f ? sqrtf(d2) : 0.f;
                if (tgi[m][q] != tgj[n]) {
                    if (dist != 0.f) {
                        float e = __expf(1.0f - dist);
                        negrow[m][q] += e;
                        if (offd) negcol[n] += e;
                    }
                } else if (grow[m][q] < gcol[n]) {
                    mycnt++;
                }
            }

    // row-side: reduce across the 16 lanes of each lane-group, 1 atomic/row
#pragma unroll
    for (int m = 0; m < 4; m++)
#pragma unroll
        for (int q = 0; q < 4; q++) {
            float v = negrow[m][q];
            v += __shfl_xor(v, 1); v += __shfl_xor(v, 2);
            v += __shfl_xor(v, 4); v += __shfl_xor(v, 8);
            if (l15 == 0) atomicAdd(&row_neg[grow[m][q]], v);
        }
    // col-side (off-diagonal tiles): reduce across lane-groups, 1 atomic/col
    if (offd) {
#pragma unroll
        for (int n = 0; n < 4; n++) {
            float v = negcol[n];
            v += __shfl_xor(v, 16); v += __shfl_xor(v, 32);
            if (lg == 0) atomicAdd(&row_neg[gcol[n]], v);
        }
    }

    // compact positive (i<j) pairs
    if (mycnt) {
        unsigned int base = atomicAdd(pair_cnt, (unsigned int)mycnt);
        unsigned int off = 0;
#pragma unroll
        for (int m = 0; m < 4; m++)
#pragma unroll
            for (int n = 0; n < 4; n++)
#pragma unroll
                for (int q = 0; q < 4; q++) {
                    if (tgi[m][q] == tgj[n] && grow[m][q] < gcol[n]) {
                        unsigned int idx = base + off;
                        if (idx < cap) {
                            float sim  = acc[m][n][q];
                            float d2   = mi[m][q] + mj[n] - 2.f * sim;
                            float dist = d2 > 0.f ? sqrtf(d2) : 0.f;
                            pairs[idx * 3 + 0] = grow[m][q];
                            pairs[idx * 3 + 1] = gcol[n];
                            pairs[idx * 3 + 2] = __float_as_int(dist);
                        }
                        off++;
                    }
                }
    }
}

__global__ void pair_kernel(const int* __restrict__ pairs,
                            const unsigned int* __restrict__ pair_cnt,
                            const float* __restrict__ row_neg,
                            unsigned int cap, double* __restrict__ loss) {
    __shared__ double red[256];
    unsigned int n = *pair_cnt;
    if (n > cap) n = cap;
    double local = 0.0;
    for (unsigned int p = blockIdx.x * blockDim.x + threadIdx.x; p < n;
         p += gridDim.x * blockDim.x) {
        int i = pairs[3 * p], j = pairs[3 * p + 1];
        float d = __int_as_float(pairs[3 * p + 2]);
        float J = logf(row_neg[i] + row_neg[j]) + d;
        if (J > 0.f) local += (double)J * (double)J;
    }
    red[threadIdx.x] = local;
    __syncthreads();
    for (int s = 128; s; s >>= 1) {
        if (threadIdx.x < (unsigned)s) red[threadIdx.x] += red[threadIdx.x + s];
        __syncthreads();
    }
    if (threadIdx.x == 0) atomicAdd(loss, red[0]);
}

__global__ void fin_kernel(const double* __restrict__ loss,
                           const unsigned int* __restrict__ pair_cnt,
                           float* __restrict__ out) {
    out[0] = (float)(*loss / (2.0 * (double)(*pair_cnt)));
}

extern "C" void kernel_launch(void* const* d_in, const int* in_sizes, int n_in,
                              void* d_out, int out_size, void* d_ws, size_t ws_size,
                              hipStream_t stream) {
    const float* X = (const float*)d_in[0];
    const int* tgt = (const int*)d_in[1];
    float* out = (float*)d_out;

    char* ws = (char*)d_ws;
    float* mag             = (float*)(ws + 0);
    float* row_neg         = (float*)(ws + 16384);
    double* loss           = (double*)(ws + 32768);
    unsigned int* pair_cnt = (unsigned int*)(ws + 32776);
    unsigned short* Xb     = (unsigned short*)(ws + XB_OFF);
    int* pairs             = (int*)(ws + PAIR_OFF);
    unsigned int cap = 0;
    if (ws_size > PAIR_OFF + 12) cap = (unsigned int)((ws_size - PAIR_OFF) / 12);

    hipMemsetAsync(ws + 16384, 0, 16400, stream);  // row_neg, loss, pair_cnt

    prep_kernel<<<NROWS / 4, 256, 0, stream>>>(X, Xb, mag);

    sim_mfma<<<NBLK, 256, 0, stream>>>(Xb, tgt, mag, row_neg, pair_cnt, pairs, cap);

    pair_kernel<<<256, 256, 0, stream>>>(pairs, pair_cnt, row_neg, cap, loss);

    fin_kernel<<<1, 1, 0, stream>>>(loss, pair_cnt, out);
}